// Round 2
// 173.984 us; speedup vs baseline: 1.0125x; 1.0125x over previous
//
#include <hip/hip_runtime.h>

// LinearAttention: B=8, N=16384 (128x128), C=96, H=4, d=24
// prep_w2 (75 blocks): zeroes kv/ksum ws + packs MFMA-ordered bf16 W frags
//     (fuses the old hipMemsetAsync + prep_w: 4 graph nodes -> 3).
// la_k1 (26.5KB LDS, 4 blocks/CU): k-GEMM with A-frags direct from global;
//     in-register rope (v_sin) + b64 transposed kqt writes; kv = K_rope^T V
//     via MFMA (A from kqt b128, V direct from global) -> global atomics.
// la_k2 (15.6KB LDS, 8 blocks/CU): q-GEMM direct-from-global A-frags; phase A
//     rope/z/kv-matvec in regs; qs buffer reused as f16 out staging with
//     pitch 98 (odd dword stride -> conflict-free; pitch 96 was ~16-way);
//     conv + coalesced f32x4 stores.
// NOTE: cooperative-launch fusion of prep+k1 was tried and is WRONG under
// graph capture / XCD L2 non-coherence (absmax 468 / 4.8e-2) — do not redo.

#define NLINE 16384
#define CCH 96
#define KTP 136    // transposed k pitch (u16): 272B rows (16B-mult)
#define QSP 98     // k2 q pitch (u16): 49 dwords, gcd(49,32)=1
#define OUTP 98    // f16 out-staging pitch (u16): conflict-free (was 96)
#define THETA_COEF 0.2768273412406135f   // log2(10000)/48
#define LOG2_2PI   2.6514961294723187f   // log2(2*pi)

typedef __attribute__((ext_vector_type(4))) float f32x4;
typedef __attribute__((ext_vector_type(8))) short bf16x8;
typedef __attribute__((ext_vector_type(2))) __fp16 fp16x2;

__device__ __forceinline__ unsigned short f2bf(float f) {
  unsigned int u = __float_as_uint(f);
  u += 0x7FFFu + ((u >> 16) & 1u);          // RNE
  return (unsigned short)(u >> 16);
}
__device__ __forceinline__ float bf2f(unsigned short h) {
  return __uint_as_float(((unsigned int)h) << 16);
}
__device__ __forceinline__ bf16x8 pack_bf8(f32x4 v0, f32x4 v1) {
  bf16x8 r;
  r[0] = (short)f2bf(v0.x); r[1] = (short)f2bf(v0.y);
  r[2] = (short)f2bf(v0.z); r[3] = (short)f2bf(v0.w);
  r[4] = (short)f2bf(v1.x); r[5] = (short)f2bf(v1.y);
  r[6] = (short)f2bf(v1.z); r[7] = (short)f2bf(v1.w);
  return r;
}

// ---------------------------------------------------------------- prep
// wfrag u = ((half*3+kk)*6+nt)*64 + lane holds
// W[half*96+nt*16+(lane&15)][kk*32+(lane>>4)*8 + 0..7]
// Also zeroes kv_g(18432) + ksum_g(768) = 19200 contiguous f32 in ws.
__global__ void prep_w2(const float* __restrict__ qkw,
                        unsigned short* __restrict__ wfrag,
                        float* __restrict__ kv_g) {
  int idx = blockIdx.x * 256 + threadIdx.x;     // 75 blocks -> 19200 threads
  if (idx < 19200) kv_g[idx] = 0.0f;            // kv_g + ksum_g contiguous
  if (idx < 2304) {
    int u = idx;
    int lane = u & 63;
    int nt = (u >> 6) % 6;
    int rest = u / 384;
    int kk = rest % 3, half = rest / 3;
    int lr = lane & 15, q4 = lane >> 4;
    const float* src = qkw + (half * 96 + nt * 16 + lr) * 96 + kk * 32 + q4 * 8;
    unsigned short* dst = wfrag + (size_t)u * 8;
#pragma unroll
    for (int j = 0; j < 8; ++j) dst[j] = f2bf(src[j]);
  }
}

// ---------------------------------------------------------------- kernel 1
__global__ __launch_bounds__(256, 4) void la_k1(
    const float* __restrict__ x, const unsigned short* __restrict__ wfrag,
    const float* __restrict__ qkb, float* __restrict__ kv_g,
    float* __restrict__ ksum_g)
{
  const int tid  = threadIdx.x;
  const int b    = blockIdx.x >> 7;
  const int tile = blockIdx.x & 127;        // image line y; rope pos = row in tile

  __shared__ alignas(16) unsigned short kqt[96 * KTP];   // 26112 B (k_rope transposed)
  __shared__ float ksum_s[96];

  if (tid < 96) ksum_s[tid] = 0.0f;
  __syncthreads();                          // init vs epilogue atomics

  const int wave = tid >> 6;
  const int lane = tid & 63;
  const int lr   = lane & 15;
  const int q4   = lane >> 4;
  const int row0 = wave * 32;
  const float* xb = x + ((size_t)b * NLINE + (size_t)tile * 128) * CCH;

  // A-fragments direct from global f32 (16 rows x 128B segments per pair)
  bf16x8 afr[2][3];
#pragma unroll
  for (int mt = 0; mt < 2; ++mt)
#pragma unroll
    for (int kk = 0; kk < 3; ++kk) {
      const float* ap = xb + (row0 + mt * 16 + lr) * CCH + kk * 32 + q4 * 8;
      afr[mt][kk] = pack_bf8(((const f32x4*)ap)[0], ((const f32x4*)ap)[1]);
    }

  float biasv[6];
#pragma unroll
  for (int nt = 0; nt < 6; ++nt) biasv[nt] = qkb[96 + nt * 16 + lr];

  // k = x @ Wk^T
  f32x4 acc[2][6];
#pragma unroll
  for (int mt = 0; mt < 2; ++mt)
#pragma unroll
    for (int nt = 0; nt < 6; ++nt) acc[mt][nt] = (f32x4){0.f, 0.f, 0.f, 0.f};

#pragma unroll
  for (int kk = 0; kk < 3; ++kk) {
#pragma unroll
    for (int nt = 0; nt < 6; ++nt) {
      bf16x8 bf = *(const bf16x8*)&wfrag[(size_t)(((3 + kk) * 6 + nt) * 64 + lane) * 8];
      acc[0][nt] = __builtin_amdgcn_mfma_f32_16x16x32_bf16(afr[0][kk], bf, acc[0][nt], 0, 0, 0);
      acc[1][nt] = __builtin_amdgcn_mfma_f32_16x16x32_bf16(afr[1][kk], bf, acc[1][nt], 0, 0, 0);
    }
  }

  // epilogue: bias+elu+1, col-sums, in-register rope, packed b64 transposed store
  const int odd = lr & 1;
#pragma unroll
  for (int nt = 0; nt < 6; ++nt) {
    const int col = nt * 16 + lr;
    const float threv = exp2f(-THETA_COEF * (float)(col >> 1) - LOG2_2PI); // theta/(2pi)
    float csum = 0.0f;
    float vv[2][4];
#pragma unroll
    for (int mt = 0; mt < 2; ++mt)
#pragma unroll
      for (int rg = 0; rg < 4; ++rg) {
        float v = acc[mt][nt][rg] + biasv[nt];
        v = (v > 0.0f) ? (v + 1.0f) : __expf(v);   // elu+1
        csum += v;
        vv[mt][rg] = v;
      }
    atomicAdd(&ksum_s[col], csum);                 // ksum over NON-roped k
#pragma unroll
    for (int mt = 0; mt < 2; ++mt) {
      unsigned long long pk = 0;
#pragma unroll
      for (int rg = 0; rg < 4; ++rg) {
        float p = __shfl_xor(vv[mt][rg], 1);       // partner col (re<->im)
        int r = row0 + mt * 16 + q4 * 4 + rg;
        float rev = (float)r * threv;
        float sn = __builtin_amdgcn_sinf(rev);     // sin(2*pi*rev) = sin(r*theta)
        float cn = __builtin_amdgcn_cosf(rev);
        float o = odd ? (p * sn + vv[mt][rg] * cn)
                      : (vv[mt][rg] * cn - p * sn);
        pk |= (unsigned long long)f2bf(o) << (16 * rg);
      }
      *(unsigned long long*)&kqt[col * KTP + row0 + mt * 16 + q4 * 4] = pk;
    }
  }
  __syncthreads();

  if (tid < 96) atomicAdd(&ksum_g[b * 96 + tid], ksum_s[tid]);

  // kv: wave = head h: D[d][e] = sum_r k_rope[r][24h+d] * v[r][24h+e]
  const int h = wave;
  f32x4 kvacc[2][2];
#pragma unroll
  for (int mt = 0; mt < 2; ++mt)
#pragma unroll
    for (int nt = 0; nt < 2; ++nt) kvacc[mt][nt] = (f32x4){0.f, 0.f, 0.f, 0.f};

#pragma unroll
  for (int kk = 0; kk < 4; ++kk) {
    const int rbase = kk * 32 + q4 * 8;
    bf16x8 ka[2], vb[2];
#pragma unroll
    for (int mt = 0; mt < 2; ++mt) {
      int c = 24 * h + mt * 16 + lr; if (c > 95) c = 95;   // garbage cells discarded
      ka[mt] = *(const bf16x8*)&kqt[c * KTP + rbase];      // aligned ds_read_b128
    }
#pragma unroll
    for (int nt = 0; nt < 2; ++nt) {
      int c = 24 * h + nt * 16 + lr; if (c > 95) c = 95;
#pragma unroll
      for (int j = 0; j < 8; ++j)
        vb[nt][j] = (short)f2bf(xb[(rbase + j) * CCH + c]);  // V direct from global (L2-hot)
    }
#pragma unroll
    for (int mt = 0; mt < 2; ++mt)
#pragma unroll
      for (int nt = 0; nt < 2; ++nt)
        kvacc[mt][nt] = __builtin_amdgcn_mfma_f32_16x16x32_bf16(ka[mt], vb[nt], kvacc[mt][nt], 0, 0, 0);
  }

  const float inv_n = 1.0f / 16384.0f;
  float* kvb = kv_g + ((size_t)b * 4 + h) * 576;
#pragma unroll
  for (int mt = 0; mt < 2; ++mt)
#pragma unroll
    for (int rg = 0; rg < 4; ++rg) {
      int d = mt * 16 + q4 * 4 + rg;
      if (d < 24) {
#pragma unroll
        for (int nt = 0; nt < 2; ++nt) {
          int e = nt * 16 + lr;
          if (e < 24) atomicAdd(&kvb[d * 24 + e], kvacc[mt][nt][rg] * inv_n);
        }
      }
    }
}

// ---------------------------------------------------------------- kernel 2
__global__ __launch_bounds__(256, 8) void la_k2(
    const float* __restrict__ x, const unsigned short* __restrict__ wfrag,
    const float* __restrict__ qkb, const float* __restrict__ lepe_w,
    const float* __restrict__ lepe_b, const float* __restrict__ kv_g,
    const float* __restrict__ ksum_g, float* __restrict__ out)
{
  const int tid = threadIdx.x;
  const int b   = blockIdx.x & 7;           // batch per XCD -> L2 locality
  const int seg = blockIdx.x >> 3;          // 64-token segment (half line)
  const int y   = seg >> 1;                 // image row (block-uniform)

  __shared__ alignas(16) unsigned short qs[64 * QSP];    // 12544 B; reused as f16 outs
  __shared__ float lepe_s[9 * 96];                       // 3456 B [tap][ch]

  for (int i = tid; i < 864; i += 256) {
    int ch = i / 9, tap = i % 9;
    lepe_s[tap * 96 + ch] = lepe_w[i];
  }

  const int wave = tid >> 6;
  const int lane = tid & 63;
  const int lr   = lane & 15;
  const int q4   = lane >> 4;

  float biasv[6];
#pragma unroll
  for (int nt = 0; nt < 6; ++nt) biasv[nt] = qkb[nt * 16 + lr];

  // A-fragments direct from global f32
  const float* xb = x + ((size_t)b * NLINE + (size_t)seg * 64) * CCH;
  bf16x8 afrag[3];
#pragma unroll
  for (int kk = 0; kk < 3; ++kk) {
    const float* ap = xb + (wave * 16 + lr) * CCH + kk * 32 + q4 * 8;
    afrag[kk] = pack_bf8(((const f32x4*)ap)[0], ((const f32x4*)ap)[1]);
  }

  // q-GEMM: wave handles tokens 16w..16w+15
  f32x4 acc[6];
#pragma unroll
  for (int nt = 0; nt < 6; ++nt) acc[nt] = (f32x4){0.f, 0.f, 0.f, 0.f};
#pragma unroll
  for (int kk = 0; kk < 3; ++kk) {
#pragma unroll
    for (int nt = 0; nt < 6; ++nt) {
      bf16x8 bf = *(const bf16x8*)&wfrag[(size_t)((kk * 6 + nt) * 64 + lane) * 8];
      acc[nt] = __builtin_amdgcn_mfma_f32_16x16x32_bf16(afrag[kk], bf, acc[nt], 0, 0, 0);
    }
  }
#pragma unroll
  for (int nt = 0; nt < 6; ++nt) {
    const int col = nt * 16 + lr;
#pragma unroll
    for (int rg = 0; rg < 4; ++rg) {
      int t = wave * 16 + q4 * 4 + rg;
      float v = acc[nt][rg] + biasv[nt];
      v = (v > 0.0f) ? (v + 1.0f) : __expf(v);
      qs[t * QSP + col] = f2bf(v);
    }
  }
  __syncthreads();

  // phase A: (token=lane, head=wave); h wave-uniform -> kv/ksum scalarize
  float res[24];
  {
    const int t  = lane;
    const int h  = __builtin_amdgcn_readfirstlane(wave);
    const int xw = ((seg & 1) << 6) + t;
    const float inv_n = 1.0f / 16384.0f;

    float qv[24];
    const unsigned int* qrow = (const unsigned int*)&qs[t * QSP + 24 * h];
#pragma unroll
    for (int u = 0; u < 12; ++u) {
      unsigned int w = qrow[u];
      qv[2 * u]     = bf2f((unsigned short)(w & 0xFFFFu));
      qv[2 * u + 1] = bf2f((unsigned short)(w >> 16));
    }

    const float* km = ksum_g + b * 96 + 24 * h;
    float dot = 0.0f;
#pragma unroll
    for (int d2 = 0; d2 < 24; ++d2) dot += qv[d2] * km[d2];   // pre-rope q
    const float z = 1.0f / (dot * inv_n + 1e-6f);

    // in-place rope on qv (v_sin/v_cos, revolutions)
#pragma unroll
    for (int jj = 0; jj < 12; ++jj) {
      float threv = exp2f(-THETA_COEF * (float)(12 * h + jj) - LOG2_2PI);
      float rev = (float)xw * threv;
      float sn = __builtin_amdgcn_sinf(rev);
      float cn = __builtin_amdgcn_cosf(rev);
      float re = qv[2 * jj], im = qv[2 * jj + 1];
      qv[2 * jj]     = re * cn - im * sn;
      qv[2 * jj + 1] = re * sn + im * cn;
    }

    const float* kvh = kv_g + ((size_t)b * 4 + h) * 576;
#pragma unroll
    for (int e = 0; e < 24; ++e) res[e] = 0.0f;
    for (int d2 = 0; d2 < 24; ++d2) {
      float qd = qv[d2];
#pragma unroll
      for (int e = 0; e < 24; ++e) res[e] += qd * kvh[d2 * 24 + e];
    }
    const float* lb = lepe_b + 24 * h;
#pragma unroll
    for (int e = 0; e < 24; ++e) res[e] = res[e] * z + lb[e];
  }
  __syncthreads();                          // all qs reads done

  // stage res -> f16 in the qs buffer, pitch 98 (odd dword stride: lane
  // stride 49 dwords, gcd(49,32)=1 -> conflict-free; 64*98*2 = 12544 B fits)
  __fp16* outs = (__fp16*)qs;
  {
    const int t = lane;
    const int h = wave;
#pragma unroll
    for (int u = 0; u < 12; ++u) {
      fp16x2 pk = __builtin_amdgcn_cvt_pkrtz(res[2 * u], res[2 * u + 1]);
      *(fp16x2*)&outs[t * OUTP + 24 * h + 2 * u] = pk;
    }
  }
  __syncthreads();

  // phase B: (token, 4ch); coalesced conv reads + flat f32x4 stores
  float* ob = out + ((size_t)b * NLINE + (size_t)seg * 64) * CCH;
  const float* xg = x + (size_t)b * NLINE * CCH;
#pragma unroll
  for (int k = 0; k < 6; ++k) {
    int idx = tid + 256 * k;
    int tl = idx / 24, c4 = idx % 24;
    int ch0 = c4 * 4;
    int xw = ((seg & 1) << 6) + tl;

    fp16x2 p0 = *(const fp16x2*)&outs[tl * OUTP + ch0];
    fp16x2 p1 = *(const fp16x2*)&outs[tl * OUTP + ch0 + 2];
    float r0 = (float)p0[0], r1 = (float)p0[1];
    float r2 = (float)p1[0], r3 = (float)p1[1];

#pragma unroll
    for (int dy = 0; dy < 3; ++dy) {
      int yy = y + dy - 1;
      if (yy < 0 || yy > 127) continue;     // block-uniform
      const float* rowp = xg + ((size_t)yy * 128) * CCH;
#pragma unroll
      for (int dx = 0; dx < 3; ++dx) {
        int xx = xw + dx - 1;
        if (xx < 0 || xx > 127) continue;   // edge lanes only
        f32x4 v = *(const f32x4*)(rowp + xx * CCH + ch0);
        const float* wp = &lepe_s[(dy * 3 + dx) * 96 + ch0];
        r0 += wp[0] * v.x;
        r1 += wp[1] * v.y;
        r2 += wp[2] * v.z;
        r3 += wp[3] * v.w;
      }
    }
    f32x4 o = { r0, r1, r2, r3 };
    ((f32x4*)ob)[idx] = o;
  }
}

// ---------------------------------------------------------------- launch
extern "C" void kernel_launch(void* const* d_in, const int* in_sizes, int n_in,
                              void* d_out, int out_size, void* d_ws, size_t ws_size,
                              hipStream_t stream) {
  const float* x      = (const float*)d_in[0];
  const float* qkw    = (const float*)d_in[1];
  const float* qkb    = (const float*)d_in[2];
  const float* lepe_w = (const float*)d_in[3];
  const float* lepe_b = (const float*)d_in[4];
  float* out = (float*)d_out;

  unsigned short* wfrag = (unsigned short*)d_ws;            // 36864 B
  float* kv_g   = (float*)((char*)d_ws + 36864);            // 18432 f32
  float* ksum_g = kv_g + 18432;                             // 768 f32 (contiguous)

  prep_w2<<<dim3(75), dim3(256), 0, stream>>>(qkw, wfrag, kv_g);
  la_k1<<<dim3(1024), dim3(256), 0, stream>>>(x, wfrag, qkb, kv_g, ksum_g);
  la_k2<<<dim3(2048), dim3(256), 0, stream>>>(x, wfrag, qkb, lepe_w, lepe_b,
                                              kv_g, ksum_g, out);
}